// Round 9
// baseline (237.154 us; speedup 1.0000x reference)
//
#include <hip/hip_runtime.h>

typedef unsigned short u16;
typedef __attribute__((ext_vector_type(8))) _Float16 half8;
typedef __attribute__((ext_vector_type(2))) __fp16 fp16x2;
typedef __attribute__((ext_vector_type(4))) float f32x4;

#define MFMAH(A,B,C) __builtin_amdgcn_mfma_f32_16x16x32_f16(A,B,C,0,0,0)
#define LOG2E 1.4426950408889634f
#define C1 0.18033688011112042f   // 0.125 * log2(e)

__device__ __forceinline__ u16 f2h(float f){
  _Float16 h = (_Float16)f; u16 r; __builtin_memcpy(&r,&h,2); return r;
}
__device__ __forceinline__ float h2f(u16 v){
  _Float16 h; __builtin_memcpy(&h,&v,2); return (float)h;
}
// two fp32 -> packed f16 pair (v_cvt_pkrtz), low = a
__device__ __forceinline__ unsigned int pack_h2(float a, float b){
  fp16x2 h = __builtin_amdgcn_cvt_pkrtz(a,b);
  unsigned int r; __builtin_memcpy(&r,&h,4); return r;
}

// async global->LDS, 16B per lane; LDS dest = wave-uniform base + lane*16.
__device__ __forceinline__ void async_ld16(const void* g, void* l) {
  __builtin_amdgcn_global_load_lds(
      (const __attribute__((address_space(1))) unsigned int*)g,
      (__attribute__((address_space(3))) unsigned int*)l, 16, 0, 0);
}

// Cast hs (4M el) + Wq,Wk,Wv,Wo (1M each) fp32->f16 into contiguous ws.
__global__ __launch_bounds__(256) void cast_all(const float* __restrict__ hs,
    const float* __restrict__ wq, const float* __restrict__ wk,
    const float* __restrict__ wv, const float* __restrict__ wo,
    u16* __restrict__ dst)
{
  unsigned int i = blockIdx.x*256 + threadIdx.x;     // chunk of 8 elements
  size_t el = (size_t)i * 8;
  const float* src; size_t off;
  if (el < 4194304) { src = hs; off = el; }
  else {
    unsigned int r = (unsigned int)((el - 4194304) >> 20);
    src = (r==0)?wq:(r==1)?wk:(r==2)?wv:wo;
    off = (el - 4194304) & 1048575;
  }
  float4 a = *reinterpret_cast<const float4*>(src+off);
  float4 b = *reinterpret_cast<const float4*>(src+off+4);
  uint4 o = {pack_h2(a.x,a.y), pack_h2(a.z,a.w), pack_h2(b.x,b.y), pack_h2(b.z,b.w)};
  *reinterpret_cast<uint4*>(dst + el) = o;
}

// QKV GEMM: C = A[M,K] @ W[N,K]^T + bias, 128x128 tiles, async staging, f16 MFMA.
// which = n/1024 routes q/k -> head layout [bh][s][d]; v -> transposed [bh][d][s].
__global__ __launch_bounds__(256) void gemm_qkv(const u16* __restrict__ A,
                                                const u16* __restrict__ W,
                                                const float* __restrict__ b0p,
                                                const float* __restrict__ b1p,
                                                const float* __restrict__ b2p,
                                                u16* __restrict__ out,
                                                int M, int N, int K)
{
  __shared__ __align__(16) u16 lds_a[128*32];
  __shared__ __align__(16) u16 lds_w[128*32];
  const int t = threadIdx.x;
  const int lane = t & 63, wave = t >> 6;
  const int wm = wave >> 1, wn = wave & 1;
  const int lr = lane & 15, quad = lane >> 4;
  const int n0 = blockIdx.x * 128, m0 = blockIdx.y * 128;
  const int wbase = t & 192;

  const f32x4 fzero = {0.f,0.f,0.f,0.f};
  f32x4 acc[4][4];
  #pragma unroll
  for (int i=0;i<4;++i)
    #pragma unroll
    for (int j=0;j<4;++j) acc[i][j] = fzero;

  for (int k0 = 0; k0 < K; k0 += 32) {
    __syncthreads();
    #pragma unroll
    for (int it=0; it<2; ++it) {
      int idx = it*256 + t;
      int row = idx >> 2, c8 = (idx & 3) * 8;
      int lbase = (it*256 + wbase) * 8;
      async_ld16(&A[(size_t)(m0+row)*K + k0 + c8], &lds_a[lbase]);
      async_ld16(&W[(size_t)(n0+row)*K + k0 + c8], &lds_w[lbase]);
    }
    __syncthreads();
    half8 af[4], bfr[4];
    #pragma unroll
    for (int mt=0; mt<4; ++mt)
      af[mt] = *reinterpret_cast<const half8*>(&lds_a[(wm*64 + mt*16 + lr)*32 + quad*8]);
    #pragma unroll
    for (int nt=0; nt<4; ++nt)
      bfr[nt] = *reinterpret_cast<const half8*>(&lds_w[(wn*64 + nt*16 + lr)*32 + quad*8]);
    #pragma unroll
    for (int mt=0; mt<4; ++mt)
      #pragma unroll
      for (int nt=0; nt<4; ++nt)
        acc[mt][nt] = MFMAH(af[mt], bfr[nt], acc[mt][nt]);
  }

  int which = n0 >> 10;
  const float* bp = (which==0) ? b0p : (which==1) ? b1p : b2p;
  u16* dst = out + (size_t)which * 4194304;
  if (which == 2) {
    // V^T: [(b*16+h)*64 + d]*2048 + s ; r -> consecutive s -> packed b64
    #pragma unroll
    for (int nt=0; nt<4; ++nt) {
      int nn = (n0 & 1023) + wn*64 + nt*16 + lr;
      float bv = bp[nn];
      int hh = nn >> 6, d = nn & 63;
      #pragma unroll
      for (int mt=0; mt<4; ++mt) {
        int m = m0 + wm*64 + mt*16 + quad*4;
        int b = m >> 11, s = m & 2047;
        uint2 o = {pack_h2(acc[mt][nt][0]+bv, acc[mt][nt][1]+bv),
                   pack_h2(acc[mt][nt][2]+bv, acc[mt][nt][3]+bv)};
        *reinterpret_cast<uint2*>(&dst[((size_t)(b*16 + hh)*64 + d)*2048 + s]) = o;
      }
    }
  } else {
    #pragma unroll
    for (int nt=0; nt<4; ++nt) {
      int nn = (n0 & 1023) + wn*64 + nt*16 + lr;
      float bv = bp[nn];
      int hh = nn >> 6, d = nn & 63;
      #pragma unroll
      for (int mt=0; mt<4; ++mt)
        #pragma unroll
        for (int r=0; r<4; ++r) {
          int m = m0 + wm*64 + mt*16 + quad*4 + r;
          int b = m >> 11, s = m & 2047;
          dst[((size_t)(b*16 + hh) * 2048 + s) * 64 + d] = f2h(acc[mt][nt][r] + bv);
        }
    }
  }
}

// Out-proj GEMM: 128M x 64N tiles (512 blocks -> 2/CU), fp32 out, f16 MFMA.
__global__ __launch_bounds__(256) void gemm_o(const u16* __restrict__ A,
                                              const u16* __restrict__ W,
                                              const float* __restrict__ bias,
                                              float* __restrict__ O,
                                              int M, int N, int K)
{
  __shared__ __align__(16) u16 lds_a[128*32];
  __shared__ __align__(16) u16 lds_w[64*32];
  const int t = threadIdx.x;
  const int lane = t & 63, wm = t >> 6;      // wave owns 32 M-rows
  const int lr = lane & 15, quad = lane >> 4;
  const int n0 = blockIdx.x * 64, m0 = blockIdx.y * 128;
  const int wbase = t & 192;

  const f32x4 fzero = {0.f,0.f,0.f,0.f};
  f32x4 acc[2][4];
  #pragma unroll
  for (int i=0;i<2;++i)
    #pragma unroll
    for (int j=0;j<4;++j) acc[i][j] = fzero;

  for (int k0 = 0; k0 < K; k0 += 32) {
    __syncthreads();
    #pragma unroll
    for (int it=0; it<2; ++it) {
      int idx = it*256 + t;
      int row = idx >> 2, c8 = (idx & 3) * 8;
      int lbase = (it*256 + wbase) * 8;
      async_ld16(&A[(size_t)(m0+row)*K + k0 + c8], &lds_a[lbase]);
    }
    async_ld16(&W[(size_t)(n0 + (t>>2))*K + k0 + (t&3)*8], &lds_w[wbase*8]);
    __syncthreads();
    half8 af[2], bfr[4];
    #pragma unroll
    for (int mt=0; mt<2; ++mt)
      af[mt] = *reinterpret_cast<const half8*>(&lds_a[(wm*32 + mt*16 + lr)*32 + quad*8]);
    #pragma unroll
    for (int nt=0; nt<4; ++nt)
      bfr[nt] = *reinterpret_cast<const half8*>(&lds_w[(nt*16 + lr)*32 + quad*8]);
    #pragma unroll
    for (int mt=0; mt<2; ++mt)
      #pragma unroll
      for (int nt=0; nt<4; ++nt)
        acc[mt][nt] = MFMAH(af[mt], bfr[nt], acc[mt][nt]);
  }

  #pragma unroll
  for (int nt=0; nt<4; ++nt) {
    int n = n0 + nt*16 + lr;
    float bv = bias[n];
    #pragma unroll
    for (int mt=0; mt<2; ++mt)
      #pragma unroll
      for (int r=0; r<4; ++r) {
        int m = m0 + wm*32 + mt*16 + quad*4 + r;
        O[(size_t)m * N + n] = acc[mt][nt][r] + bv;
      }
  }
}

// In-place RMSNorm (over the 1024 pre-split channels) + RoPE on [B,H,S,D] f16.
__global__ __launch_bounds__(256) void rmsrope(u16* __restrict__ qb, u16* __restrict__ kb,
                                               const float* __restrict__ cosb,
                                               const float* __restrict__ sinb,
                                               const float* __restrict__ w)
{
  u16* buf = blockIdx.y ? kb : qb;
  const int bs = blockIdx.x;
  const int b = bs >> 11, s = bs & 2047;
  const int t = threadIdx.x;
  float x1[2], x2[2];
  float ss = 0.f;
  #pragma unroll
  for (int i=0;i<2;++i){
    int p = t + i*256;
    int h = p >> 5, d = p & 31;
    size_t base = ((size_t)(b*16+h)*2048 + s)*64;
    x1[i] = h2f(buf[base + d]);
    x2[i] = h2f(buf[base + d + 32]);
    ss += x1[i]*x1[i] + x2[i]*x2[i];
  }
  #pragma unroll
  for (int off=32; off>0; off>>=1) ss += __shfl_xor(ss, off, 64);
  __shared__ float red[4];
  if ((t & 63) == 0) red[t>>6] = ss;
  __syncthreads();
  float tot = red[0]+red[1]+red[2]+red[3];
  float r = rsqrtf(tot * (1.0f/1024.0f) + 1e-6f);
  #pragma unroll
  for (int i=0;i<2;++i){
    int p = t + i*256;
    int h = p >> 5, d = p & 31;
    size_t base = ((size_t)(b*16+h)*2048 + s)*64;
    float w1 = w[h*64+d], w2 = w[h*64+d+32];
    float n1 = x1[i]*r*w1, n2 = x2[i]*r*w2;
    float c1 = cosb[s*64+d],    s1 = sinb[s*64+d];
    float c2 = cosb[s*64+d+32], s2 = sinb[s*64+d+32];
    buf[base+d]    = f2h(n1*c1 - n2*s1);
    buf[base+d+32] = f2h(n2*c2 + n1*s2);
  }
}

// Flash attention, transposed-score formulation, BLOCK_Q=128, 8 waves.
//   S^T = K·Q^T  -> C-layout: lane holds P^T[key=ksub*16+quad*4+r][q=lr]
//   O^T = V^T·P^T with vbuf in virtual-k order -> aligned b128 frags everywhere.
// Virtual-k pos(key): u=key>>5, s=(key>>4)&1, qd=(key>>2)&3, r=key&3 -> u*32+qd*8+s*4+r.
// Staging thread slot covers pos slot*8..slot*8+7 = keys {u*32+qd*4+0..3, +16..+19}.
__global__ __launch_bounds__(512) void attn(const u16* __restrict__ qh,
                                            const u16* __restrict__ kh,
                                            const u16* __restrict__ vt,
                                            u16* __restrict__ ao)
{
  __shared__ __align__(16) u16 kbuf[64*72];     // [key][d], pad 72
  __shared__ __align__(16) u16 vbuf[64*72];     // [d][virtual-k], pad 72
  const int t = threadIdx.x;
  const int lane = t & 63, w = t >> 6;          // 8 waves
  const int lr = lane & 15, quad = lane >> 4;
  const int bx = blockIdx.x;
  const int qbase = bx * 128;
  const int bh = blockIdx.y;
  const int b = bh >> 4, h = bh & 15;
  const size_t hb = (size_t)bh * 2048 * 64;
  const u16* qp = qh + hb;
  const u16* kp = kh + hb;
  const u16* vtp = vt + hb;

  const int q_abs = qbase + w*16 + lr;
  half8 qf0 = *reinterpret_cast<const half8*>(&qp[(size_t)q_abs*64 + quad*8]);
  half8 qf1 = *reinterpret_cast<const half8*>(&qp[(size_t)q_abs*64 + 32 + quad*8]);

  // staging: thread owns one 16B chunk of kbuf row + one 16B virtual-k chunk of vbuf row
  const int row = t >> 3;                       // 0..63
  const int cc = t & 7;
  const int vu = cc >> 2, vq = cc & 3;
  const int k1 = vu*32 + vq*4;                  // vbuf source key bases: k1, k1+16
  u16* kw = &kbuf[row*72 + cc*8];
  u16* vw = &vbuf[row*72 + cc*8];
  const u16* kg = kp + (size_t)row*64 + cc*8;
  const u16* vg = vtp + (size_t)row*2048 + k1;

  const f32x4 fzero = {0.f,0.f,0.f,0.f};
  f32x4 oacc[4];
  #pragma unroll
  for (int i=0;i<4;++i) oacc[i] = fzero;
  float lsum = 0.f;
  const int diag = (qbase + w*16) >> 6;         // the one mixed tile for this wave

  for (int kt=0; kt<32; ++kt) {
    __syncthreads();
    {
      uint4 kv = *reinterpret_cast<const uint4*>(kg + (size_t)kt*4096);
      uint2 g1 = *reinterpret_cast<const uint2*>(vg + kt*64);
      uint2 g2 = *reinterpret_cast<const uint2*>(vg + kt*64 + 16);
      *reinterpret_cast<uint4*>(kw) = kv;
      uint4 vv = {g1.x, g1.y, g2.x, g2.y};
      *reinterpret_cast<uint4*>(vw) = vv;
    }
    __syncthreads();

    // S^T = K · Q^T
    f32x4 zz[4];
    #pragma unroll
    for (int ksub=0; ksub<4; ++ksub) {
      const u16* kr = &kbuf[(ksub*16+lr)*72 + quad*8];
      half8 a0, a1;
      __builtin_memcpy(&a0, kr, 16);
      __builtin_memcpy(&a1, kr+32, 16);
      f32x4 z = fzero;
      z = MFMAH(a0, qf0, z);
      z = MFMAH(a1, qf1, z);
      zz[ksub] = z;
    }

    // P = exp(S/8 + mask); mask wave-uniform except the diagonal tile
    unsigned int pk[4][2];
    if (kt != diag) {
      float ml = (kt < diag) ? LOG2E : 0.0f;
      #pragma unroll
      for (int ksub=0; ksub<4; ++ksub) {
        float p0 = __builtin_amdgcn_exp2f(__builtin_fmaf(zz[ksub][0], C1, ml));
        float p1 = __builtin_amdgcn_exp2f(__builtin_fmaf(zz[ksub][1], C1, ml));
        float p2 = __builtin_amdgcn_exp2f(__builtin_fmaf(zz[ksub][2], C1, ml));
        float p3 = __builtin_amdgcn_exp2f(__builtin_fmaf(zz[ksub][3], C1, ml));
        lsum += (p0+p1) + (p2+p3);
        pk[ksub][0] = pack_h2(p0, p1);
        pk[ksub][1] = pack_h2(p2, p3);
      }
    } else {
      #pragma unroll
      for (int ksub=0; ksub<4; ++ksub) {
        int key0 = kt*64 + ksub*16 + quad*4;
        float p[4];
        #pragma unroll
        for (int r=0; r<4; ++r) {
          float ml = (key0 + r <= q_abs) ? LOG2E : 0.0f;
          p[r] = __builtin_amdgcn_exp2f(__builtin_fmaf(zz[ksub][r], C1, ml));
          lsum += p[r];
        }
        pk[ksub][0] = pack_h2(p[0], p[1]);
        pk[ksub][1] = pack_h2(p[2], p[3]);
      }
    }

    // O^T += V^T · P^T
    #pragma unroll
    for (int u=0; u<2; ++u) {
      uint4 pq = {pk[2*u][0], pk[2*u][1], pk[2*u+1][0], pk[2*u+1][1]};
      half8 pf;
      __builtin_memcpy(&pf, &pq, 16);
      #pragma unroll
      for (int dt=0; dt<4; ++dt) {
        half8 vf;
        __builtin_memcpy(&vf, &vbuf[(dt*16+lr)*72 + u*32 + quad*8], 16);
        oacc[dt] = MFMAH(vf, pf, oacc[dt]);
      }
    }
  }

  lsum += __shfl_xor(lsum, 16, 64);
  lsum += __shfl_xor(lsum, 32, 64);
  float inv = 1.0f / lsum;
  size_t rowbase = ((size_t)(b*2048 + q_abs))*1024 + h*64;
  #pragma unroll
  for (int dt=0; dt<4; ++dt) {
    uint2 o = {pack_h2(oacc[dt][0]*inv, oacc[dt][1]*inv),
               pack_h2(oacc[dt][2]*inv, oacc[dt][3]*inv)};
    *reinterpret_cast<uint2*>(&ao[rowbase + dt*16 + quad*4]) = o;
  }
}

extern "C" void kernel_launch(void* const* d_in, const int* in_sizes, int n_in,
                              void* d_out, int out_size, void* d_ws, size_t ws_size,
                              hipStream_t stream)
{
  const float* hs   = (const float*)d_in[0];
  const float* cosb = (const float*)d_in[1];
  const float* sinb = (const float*)d_in[2];
  const float* Wq   = (const float*)d_in[3];
  const float* bq   = (const float*)d_in[4];
  const float* Wk   = (const float*)d_in[5];
  const float* bk   = (const float*)d_in[6];
  const float* Wv   = (const float*)d_in[7];
  const float* bv   = (const float*)d_in[8];
  const float* Wo   = (const float*)d_in[9];
  const float* bo   = (const float*)d_in[10];
  const float* rw   = (const float*)d_in[11];

  const size_t NEL = (size_t)4096 * 1024;   // 4M
  const size_t WEL = (size_t)1024 * 1024;   // 1M
  u16* hsb = (u16*)d_ws;                    // f16 hs [4096,1024]
  u16* wqb = hsb + NEL;                     // Wq,Wk,Wv contiguous (fused QKV GEMM)
  u16* wob = wqb + 3*WEL;
  u16* qhb = wob + WEL;                     // q,k head layout; v -> V^T [bh][d][s]
  u16* khb = qhb + NEL;
  u16* vtb = khb + NEL;
  u16* aob = hsb;                           // reuse: hs consumed by QKV GEMM

  cast_all<<<4096, 256, 0, stream>>>(hs, Wq, Wk, Wv, Wo, hsb);
  gemm_qkv<<<dim3(24,32), 256, 0, stream>>>(hsb, wqb, bq, bk, bv, qhb, 4096, 3072, 1024);
  rmsrope<<<dim3(4096,2), 256, 0, stream>>>(qhb, khb, cosb, sinb, rw);
  attn<<<dim3(16,32), 512, 0, stream>>>(qhb, khb, vtb, aob);
  gemm_o<<<dim3(16,32), 256, 0, stream>>>(aob, wob, bo, (float*)d_out, 4096, 1024, 1024);
}

// Round 10
// 234.549 us; speedup vs baseline: 1.0111x; 1.0111x over previous
//
#include <hip/hip_runtime.h>

typedef unsigned short u16;
typedef __attribute__((ext_vector_type(8))) _Float16 half8;
typedef __attribute__((ext_vector_type(2))) __fp16 fp16x2;
typedef __attribute__((ext_vector_type(4))) float f32x4;

#define MFMAH(A,B,C) __builtin_amdgcn_mfma_f32_16x16x32_f16(A,B,C,0,0,0)
#define LOG2E 1.4426950408889634f
#define C1 0.18033688011112042f   // 0.125 * log2(e)

__device__ __forceinline__ u16 f2h(float f){
  _Float16 h = (_Float16)f; u16 r; __builtin_memcpy(&r,&h,2); return r;
}
__device__ __forceinline__ float h2f(u16 v){
  _Float16 h; __builtin_memcpy(&h,&v,2); return (float)h;
}
// two fp32 -> packed f16 pair (v_cvt_pkrtz), low = a
__device__ __forceinline__ unsigned int pack_h2(float a, float b){
  fp16x2 h = __builtin_amdgcn_cvt_pkrtz(a,b);
  unsigned int r; __builtin_memcpy(&r,&h,4); return r;
}

// async global->LDS, 16B per lane; LDS dest = wave-uniform base + lane*16.
__device__ __forceinline__ void async_ld16(const void* g, void* l) {
  __builtin_amdgcn_global_load_lds(
      (const __attribute__((address_space(1))) unsigned int*)g,
      (__attribute__((address_space(3))) unsigned int*)l, 16, 0, 0);
}

// Cast hs (4M el) + Wq,Wk,Wv,Wo (1M each) fp32->f16 into contiguous ws.
__global__ __launch_bounds__(256) void cast_all(const float* __restrict__ hs,
    const float* __restrict__ wq, const float* __restrict__ wk,
    const float* __restrict__ wv, const float* __restrict__ wo,
    u16* __restrict__ dst)
{
  unsigned int i = blockIdx.x*256 + threadIdx.x;     // chunk of 8 elements
  size_t el = (size_t)i * 8;
  const float* src; size_t off;
  if (el < 4194304) { src = hs; off = el; }
  else {
    unsigned int r = (unsigned int)((el - 4194304) >> 20);
    src = (r==0)?wq:(r==1)?wk:(r==2)?wv:wo;
    off = (el - 4194304) & 1048575;
  }
  float4 a = *reinterpret_cast<const float4*>(src+off);
  float4 b = *reinterpret_cast<const float4*>(src+off+4);
  uint4 o = {pack_h2(a.x,a.y), pack_h2(a.z,a.w), pack_h2(b.x,b.y), pack_h2(b.z,b.w)};
  *reinterpret_cast<uint4*>(dst + el) = o;
}

// Q/K GEMM with SWAPPED MFMA operands: D[n][m] C-layout -> lane holds 4 consecutive
// n (= d within head) -> packed uint2 stores into head layout [bh][s][d].
// W = [Wq;Wk] (N=2048 rows); which = n0>>10 routes q vs k.
__global__ __launch_bounds__(256) void gemm_qk(const u16* __restrict__ A,
                                               const u16* __restrict__ W,
                                               const float* __restrict__ bqp,
                                               const float* __restrict__ bkp,
                                               u16* __restrict__ qout,
                                               u16* __restrict__ kout,
                                               int M, int N, int K)
{
  __shared__ __align__(16) u16 lds_a[128*32];
  __shared__ __align__(16) u16 lds_w[128*32];
  const int t = threadIdx.x;
  const int lane = t & 63, wave = t >> 6;
  const int wm = wave >> 1, wn = wave & 1;
  const int lr = lane & 15, quad = lane >> 4;
  const int n0 = blockIdx.x * 128, m0 = blockIdx.y * 128;
  const int wbase = t & 192;

  const f32x4 fzero = {0.f,0.f,0.f,0.f};
  f32x4 acc[4][4];
  #pragma unroll
  for (int i=0;i<4;++i)
    #pragma unroll
    for (int j=0;j<4;++j) acc[i][j] = fzero;

  for (int k0 = 0; k0 < K; k0 += 32) {
    __syncthreads();
    #pragma unroll
    for (int it=0; it<2; ++it) {
      int idx = it*256 + t;
      int row = idx >> 2, c8 = (idx & 3) * 8;
      int lbase = (it*256 + wbase) * 8;
      async_ld16(&A[(size_t)(m0+row)*K + k0 + c8], &lds_a[lbase]);
      async_ld16(&W[(size_t)(n0+row)*K + k0 + c8], &lds_w[lbase]);
    }
    __syncthreads();
    half8 af[4], bfr[4];
    #pragma unroll
    for (int mt=0; mt<4; ++mt)
      af[mt] = *reinterpret_cast<const half8*>(&lds_a[(wm*64 + mt*16 + lr)*32 + quad*8]);
    #pragma unroll
    for (int nt=0; nt<4; ++nt)
      bfr[nt] = *reinterpret_cast<const half8*>(&lds_w[(wn*64 + nt*16 + lr)*32 + quad*8]);
    #pragma unroll
    for (int mt=0; mt<4; ++mt)
      #pragma unroll
      for (int nt=0; nt<4; ++nt)
        acc[mt][nt] = MFMAH(bfr[nt], af[mt], acc[mt][nt]);   // SWAPPED: D[n][m]
  }

  int which = n0 >> 10;
  const float* bp = which ? bkp : bqp;
  u16* dst = which ? kout : qout;
  #pragma unroll
  for (int nt=0; nt<4; ++nt) {
    int nn = (n0 & 1023) + wn*64 + nt*16 + quad*4;   // 4 consecutive n on r
    float4 bv = *reinterpret_cast<const float4*>(&bp[nn]);
    int hh = nn >> 6, d4 = nn & 63;
    #pragma unroll
    for (int mt=0; mt<4; ++mt) {
      int m = m0 + wm*64 + mt*16 + lr;
      int b = m >> 11, s = m & 2047;
      uint2 o = {pack_h2(acc[mt][nt][0]+bv.x, acc[mt][nt][1]+bv.y),
                 pack_h2(acc[mt][nt][2]+bv.z, acc[mt][nt][3]+bv.w)};
      *reinterpret_cast<uint2*>(&dst[((size_t)(b*16 + hh)*2048 + s)*64 + d4]) = o;
    }
  }
}

// V GEMM, original operand order: lane holds 4 consecutive m (= s) -> packed uint2
// stores into V^T layout [bh][d][s].
__global__ __launch_bounds__(256) void gemm_v(const u16* __restrict__ A,
                                              const u16* __restrict__ W,
                                              const float* __restrict__ bvp,
                                              u16* __restrict__ vout,
                                              int M, int N, int K)
{
  __shared__ __align__(16) u16 lds_a[128*32];
  __shared__ __align__(16) u16 lds_w[128*32];
  const int t = threadIdx.x;
  const int lane = t & 63, wave = t >> 6;
  const int wm = wave >> 1, wn = wave & 1;
  const int lr = lane & 15, quad = lane >> 4;
  const int n0 = blockIdx.x * 128, m0 = blockIdx.y * 128;
  const int wbase = t & 192;

  const f32x4 fzero = {0.f,0.f,0.f,0.f};
  f32x4 acc[4][4];
  #pragma unroll
  for (int i=0;i<4;++i)
    #pragma unroll
    for (int j=0;j<4;++j) acc[i][j] = fzero;

  for (int k0 = 0; k0 < K; k0 += 32) {
    __syncthreads();
    #pragma unroll
    for (int it=0; it<2; ++it) {
      int idx = it*256 + t;
      int row = idx >> 2, c8 = (idx & 3) * 8;
      int lbase = (it*256 + wbase) * 8;
      async_ld16(&A[(size_t)(m0+row)*K + k0 + c8], &lds_a[lbase]);
      async_ld16(&W[(size_t)(n0+row)*K + k0 + c8], &lds_w[lbase]);
    }
    __syncthreads();
    half8 af[4], bfr[4];
    #pragma unroll
    for (int mt=0; mt<4; ++mt)
      af[mt] = *reinterpret_cast<const half8*>(&lds_a[(wm*64 + mt*16 + lr)*32 + quad*8]);
    #pragma unroll
    for (int nt=0; nt<4; ++nt)
      bfr[nt] = *reinterpret_cast<const half8*>(&lds_w[(wn*64 + nt*16 + lr)*32 + quad*8]);
    #pragma unroll
    for (int mt=0; mt<4; ++mt)
      #pragma unroll
      for (int nt=0; nt<4; ++nt)
        acc[mt][nt] = MFMAH(af[mt], bfr[nt], acc[mt][nt]);   // D[m][n]
  }

  #pragma unroll
  for (int nt=0; nt<4; ++nt) {
    int nn = n0 + wn*64 + nt*16 + lr;
    float bv = bvp[nn];
    int hh = nn >> 6, d = nn & 63;
    #pragma unroll
    for (int mt=0; mt<4; ++mt) {
      int m = m0 + wm*64 + mt*16 + quad*4;
      int b = m >> 11, s = m & 2047;
      uint2 o = {pack_h2(acc[mt][nt][0]+bv, acc[mt][nt][1]+bv),
                 pack_h2(acc[mt][nt][2]+bv, acc[mt][nt][3]+bv)};
      *reinterpret_cast<uint2*>(&vout[((size_t)(b*16 + hh)*64 + d)*2048 + s]) = o;
    }
  }
}

// Out-proj GEMM, SWAPPED operands: lane holds 4 consecutive n -> float4 stores.
// 128M x 64N tiles (512 blocks).
__global__ __launch_bounds__(256) void gemm_o(const u16* __restrict__ A,
                                              const u16* __restrict__ W,
                                              const float* __restrict__ bias,
                                              float* __restrict__ O,
                                              int M, int N, int K)
{
  __shared__ __align__(16) u16 lds_a[128*32];
  __shared__ __align__(16) u16 lds_w[64*32];
  const int t = threadIdx.x;
  const int lane = t & 63, wm = t >> 6;      // wave owns 32 M-rows
  const int lr = lane & 15, quad = lane >> 4;
  const int n0 = blockIdx.x * 64, m0 = blockIdx.y * 128;
  const int wbase = t & 192;

  const f32x4 fzero = {0.f,0.f,0.f,0.f};
  f32x4 acc[2][4];
  #pragma unroll
  for (int i=0;i<2;++i)
    #pragma unroll
    for (int j=0;j<4;++j) acc[i][j] = fzero;

  for (int k0 = 0; k0 < K; k0 += 32) {
    __syncthreads();
    #pragma unroll
    for (int it=0; it<2; ++it) {
      int idx = it*256 + t;
      int row = idx >> 2, c8 = (idx & 3) * 8;
      int lbase = (it*256 + wbase) * 8;
      async_ld16(&A[(size_t)(m0+row)*K + k0 + c8], &lds_a[lbase]);
    }
    async_ld16(&W[(size_t)(n0 + (t>>2))*K + k0 + (t&3)*8], &lds_w[wbase*8]);
    __syncthreads();
    half8 af[2], bfr[4];
    #pragma unroll
    for (int mt=0; mt<2; ++mt)
      af[mt] = *reinterpret_cast<const half8*>(&lds_a[(wm*32 + mt*16 + lr)*32 + quad*8]);
    #pragma unroll
    for (int nt=0; nt<4; ++nt)
      bfr[nt] = *reinterpret_cast<const half8*>(&lds_w[(nt*16 + lr)*32 + quad*8]);
    #pragma unroll
    for (int mt=0; mt<2; ++mt)
      #pragma unroll
      for (int nt=0; nt<4; ++nt)
        acc[mt][nt] = MFMAH(bfr[nt], af[mt], acc[mt][nt]);   // SWAPPED: D[n][m]
  }

  #pragma unroll
  for (int nt=0; nt<4; ++nt) {
    int nb = n0 + nt*16 + quad*4;              // 4 consecutive n on r
    float4 bv = *reinterpret_cast<const float4*>(&bias[nb]);
    #pragma unroll
    for (int mt=0; mt<2; ++mt) {
      int m = m0 + wm*32 + mt*16 + lr;
      float4 o = {acc[mt][nt][0]+bv.x, acc[mt][nt][1]+bv.y,
                  acc[mt][nt][2]+bv.z, acc[mt][nt][3]+bv.w};
      *reinterpret_cast<float4*>(&O[(size_t)m * N + nb]) = o;
    }
  }
}

// In-place RMSNorm (over 1024 pre-split channels) + RoPE on [B,H,S,D] f16.
// 128 threads/block, vectorized uint2/float4. blockIdx.y selects q/k.
__global__ __launch_bounds__(128) void rmsrope(u16* __restrict__ qb, u16* __restrict__ kb,
                                               const float* __restrict__ cosb,
                                               const float* __restrict__ sinb,
                                               const float* __restrict__ w)
{
  u16* buf = blockIdx.y ? kb : qb;
  const int bs = blockIdx.x;
  const int b = bs >> 11, s = bs & 2047;
  const int t = threadIdx.x;                 // 128
  const int h = t >> 3, d0 = (t & 7) * 4;
  size_t base = ((size_t)(b*16+h)*2048 + s)*64;

  uint2 u1 = *reinterpret_cast<const uint2*>(&buf[base + d0]);
  uint2 u2 = *reinterpret_cast<const uint2*>(&buf[base + d0 + 32]);
  u16 a1[4], a2[4];
  __builtin_memcpy(a1, &u1, 8); __builtin_memcpy(a2, &u2, 8);
  float x1[4], x2[4];
  float ss = 0.f;
  #pragma unroll
  for (int j=0;j<4;++j){
    x1[j] = h2f(a1[j]); x2[j] = h2f(a2[j]);
    ss += x1[j]*x1[j] + x2[j]*x2[j];
  }
  #pragma unroll
  for (int off=32; off>0; off>>=1) ss += __shfl_xor(ss, off, 64);
  __shared__ float red[2];
  if ((t & 63) == 0) red[t>>6] = ss;
  __syncthreads();
  float tot = red[0] + red[1];
  float r = rsqrtf(tot * (1.0f/1024.0f) + 1e-6f);

  float4 w1 = *reinterpret_cast<const float4*>(&w[h*64+d0]);
  float4 w2 = *reinterpret_cast<const float4*>(&w[h*64+d0+32]);
  float4 c1 = *reinterpret_cast<const float4*>(&cosb[s*64+d0]);
  float4 s1 = *reinterpret_cast<const float4*>(&sinb[s*64+d0]);
  float4 c2 = *reinterpret_cast<const float4*>(&cosb[s*64+d0+32]);
  float4 s2 = *reinterpret_cast<const float4*>(&sinb[s*64+d0+32]);
  float n1[4] = {x1[0]*r*w1.x, x1[1]*r*w1.y, x1[2]*r*w1.z, x1[3]*r*w1.w};
  float n2[4] = {x2[0]*r*w2.x, x2[1]*r*w2.y, x2[2]*r*w2.z, x2[3]*r*w2.w};
  float o1[4] = {n1[0]*c1.x - n2[0]*s1.x, n1[1]*c1.y - n2[1]*s1.y,
                 n1[2]*c1.z - n2[2]*s1.z, n1[3]*c1.w - n2[3]*s1.w};
  float o2[4] = {n2[0]*c2.x + n1[0]*s2.x, n2[1]*c2.y + n1[1]*s2.y,
                 n2[2]*c2.z + n1[2]*s2.z, n2[3]*c2.w + n1[3]*s2.w};
  uint2 v1 = {pack_h2(o1[0],o1[1]), pack_h2(o1[2],o1[3])};
  uint2 v2 = {pack_h2(o2[0],o2[1]), pack_h2(o2[2],o2[3])};
  *reinterpret_cast<uint2*>(&buf[base + d0])      = v1;
  *reinterpret_cast<uint2*>(&buf[base + d0 + 32]) = v2;
}

// Flash attention, transposed-score formulation, BLOCK_Q=128, 8 waves,
// DOUBLE-BUFFERED staging (register prefetch, one barrier per tile).
//   S^T = K·Q^T ; O^T = V^T·P^T with vbuf in virtual-k order.
__global__ __launch_bounds__(512) void attn(const u16* __restrict__ qh,
                                            const u16* __restrict__ kh,
                                            const u16* __restrict__ vt,
                                            u16* __restrict__ ao)
{
  __shared__ __align__(16) u16 kbuf[2][64*72];
  __shared__ __align__(16) u16 vbuf[2][64*72];
  const int t = threadIdx.x;
  const int lane = t & 63, w = t >> 6;          // 8 waves
  const int lr = lane & 15, quad = lane >> 4;
  const int bx = blockIdx.x;
  const int qbase = bx * 128;
  const int bh = blockIdx.y;
  const int b = bh >> 4, h = bh & 15;
  const size_t hb = (size_t)bh * 2048 * 64;
  const u16* qp = qh + hb;
  const u16* kp = kh + hb;
  const u16* vtp = vt + hb;

  const int q_abs = qbase + w*16 + lr;
  half8 qf0 = *reinterpret_cast<const half8*>(&qp[(size_t)q_abs*64 + quad*8]);
  half8 qf1 = *reinterpret_cast<const half8*>(&qp[(size_t)q_abs*64 + 32 + quad*8]);

  // staging: thread owns one 16B chunk of kbuf row + one 16B virtual-k chunk of vbuf row
  const int row = t >> 3;                       // 0..63
  const int cc = t & 7;
  const int vu = cc >> 2, vq = cc & 3;
  const int k1 = vu*32 + vq*4;                  // vbuf source key bases: k1, k1+16
  const int kofs = row*72 + cc*8;
  const u16* kg = kp + (size_t)row*64 + cc*8;
  const u16* vg = vtp + (size_t)row*2048 + k1;

  const f32x4 fzero = {0.f,0.f,0.f,0.f};
  f32x4 oacc[4];
  #pragma unroll
  for (int i=0;i<4;++i) oacc[i] = fzero;
  float lsum = 0.f;
  const int diag = (qbase + w*16) >> 6;         // the one mixed tile for this wave

  // stage tile 0 into buffer 0
  {
    uint4 kv = *reinterpret_cast<const uint4*>(kg);
    uint2 g1 = *reinterpret_cast<const uint2*>(vg);
    uint2 g2 = *reinterpret_cast<const uint2*>(vg + 16);
    *reinterpret_cast<uint4*>(&kbuf[0][kofs]) = kv;
    uint4 vv = {g1.x, g1.y, g2.x, g2.y};
    *reinterpret_cast<uint4*>(&vbuf[0][kofs]) = vv;
  }

  for (int kt=0; kt<32; ++kt) {
    // prefetch next tile into registers (overlaps with compute below)
    uint4 kvn; uint2 g1n, g2n;
    if (kt < 31) {
      kvn = *reinterpret_cast<const uint4*>(kg + (size_t)(kt+1)*4096);
      g1n = *reinterpret_cast<const uint2*>(vg + (kt+1)*64);
      g2n = *reinterpret_cast<const uint2*>(vg + (kt+1)*64 + 16);
    }
    __syncthreads();                            // buf[kt&1] visible; prev readers done
    const u16* kb = kbuf[kt & 1];
    const u16* vb = vbuf[kt & 1];

    // S^T = K · Q^T
    f32x4 zz[4];
    #pragma unroll
    for (int ksub=0; ksub<4; ++ksub) {
      const u16* kr = &kb[(ksub*16+lr)*72 + quad*8];
      half8 a0, a1;
      __builtin_memcpy(&a0, kr, 16);
      __builtin_memcpy(&a1, kr+32, 16);
      f32x4 z = fzero;
      z = MFMAH(a0, qf0, z);
      z = MFMAH(a1, qf1, z);
      zz[ksub] = z;
    }

    // P = exp(S/8 + mask); mask wave-uniform except the diagonal tile
    unsigned int pk[4][2];
    if (kt != diag) {
      float ml = (kt < diag) ? LOG2E : 0.0f;
      #pragma unroll
      for (int ksub=0; ksub<4; ++ksub) {
        float p0 = __builtin_amdgcn_exp2f(__builtin_fmaf(zz[ksub][0], C1, ml));
        float p1 = __builtin_amdgcn_exp2f(__builtin_fmaf(zz[ksub][1], C1, ml));
        float p2 = __builtin_amdgcn_exp2f(__builtin_fmaf(zz[ksub][2], C1, ml));
        float p3 = __builtin_amdgcn_exp2f(__builtin_fmaf(zz[ksub][3], C1, ml));
        lsum += (p0+p1) + (p2+p3);
        pk[ksub][0] = pack_h2(p0, p1);
        pk[ksub][1] = pack_h2(p2, p3);
      }
    } else {
      #pragma unroll
      for (int ksub=0; ksub<4; ++ksub) {
        int key0 = kt*64 + ksub*16 + quad*4;
        float p[4];
        #pragma unroll
        for (int r=0; r<4; ++r) {
          float ml = (key0 + r <= q_abs) ? LOG2E : 0.0f;
          p[r] = __builtin_amdgcn_exp2f(__builtin_fmaf(zz[ksub][r], C1, ml));
          lsum += p[r];
        }
        pk[ksub][0] = pack_h2(p[0], p[1]);
        pk[ksub][1] = pack_h2(p[2], p[3]);
      }
    }

    // O^T += V^T · P^T
    #pragma unroll
    for (int u=0; u<2; ++u) {
      uint4 pq = {pk[2*u][0], pk[2*u][1], pk[2*u+1][0], pk[2*u+1][1]};
      half8 pf;
      __builtin_memcpy(&pf, &pq, 16);
      #pragma unroll
      for (int dt=0; dt<4; ++dt) {
        half8 vf;
        __builtin_memcpy(&vf, &vb[(dt*16+lr)*72 + u*32 + quad*8], 16);
        oacc[dt] = MFMAH(vf, pf, oacc[dt]);
      }
    }

    // write prefetched tile into the other buffer (visible after next barrier)
    if (kt < 31) {
      *reinterpret_cast<uint4*>(&kbuf[(kt+1)&1][kofs]) = kvn;
      uint4 vv = {g1n.x, g1n.y, g2n.x, g2n.y};
      *reinterpret_cast<uint4*>(&vbuf[(kt+1)&1][kofs]) = vv;
    }
  }

  lsum += __shfl_xor(lsum, 16, 64);
  lsum += __shfl_xor(lsum, 32, 64);
  float inv = 1.0f / lsum;
  size_t rowbase = ((size_t)(b*2048 + q_abs))*1024 + h*64;
  #pragma unroll
  for (int dt=0; dt<4; ++dt) {
    uint2 o = {pack_h2(oacc[dt][0]*inv, oacc[dt][1]*inv),
               pack_h2(oacc[dt][2]*inv, oacc[dt][3]*inv)};
    *reinterpret_cast<uint2*>(&ao[rowbase + dt*16 + quad*4]) = o;
  }
}

extern "C" void kernel_launch(void* const* d_in, const int* in_sizes, int n_in,
                              void* d_out, int out_size, void* d_ws, size_t ws_size,
                              hipStream_t stream)
{
  const float* hs   = (const float*)d_in[0];
  const float* cosb = (const float*)d_in[1];
  const float* sinb = (const float*)d_in[2];
  const float* Wq   = (const float*)d_in[3];
  const float* bq   = (const float*)d_in[4];
  const float* Wk   = (const float*)d_in[5];
  const float* bk   = (const float*)d_in[6];
  const float* Wv   = (const float*)d_in[7];
  const float* bv   = (const float*)d_in[8];
  const float* Wo   = (const float*)d_in[9];
  const float* bo   = (const float*)d_in[10];
  const float* rw   = (const float*)d_in[11];

  const size_t NEL = (size_t)4096 * 1024;   // 4M
  const size_t WEL = (size_t)1024 * 1024;   // 1M
  u16* hsb = (u16*)d_ws;                    // f16 hs [4096,1024]
  u16* wqb = hsb + NEL;                     // Wq,Wk contiguous; then Wv, Wo
  u16* wvb = wqb + 2*WEL;
  u16* wob = wqb + 3*WEL;
  u16* qhb = wob + WEL;                     // q,k head layout; v -> V^T [bh][d][s]
  u16* khb = qhb + NEL;
  u16* vtb = khb + NEL;
  u16* aob = hsb;                           // reuse: hs consumed by QKV GEMMs

  cast_all<<<4096, 256, 0, stream>>>(hs, Wq, Wk, Wv, Wo, hsb);
  gemm_qk<<<dim3(16,32), 256, 0, stream>>>(hsb, wqb, bq, bk, qhb, khb, 4096, 2048, 1024);
  gemm_v<<<dim3(8,32), 256, 0, stream>>>(hsb, wvb, bv, vtb, 4096, 1024, 1024);
  rmsrope<<<dim3(4096,2), 128, 0, stream>>>(qhb, khb, cosb, sinb, rw);
  attn<<<dim3(16,32), 512, 0, stream>>>(qhb, khb, vtb, aob);
  gemm_o<<<dim3(16,32), 256, 0, stream>>>(aob, wob, bo, (float*)d_out, 4096, 1024, 1024);
}

// Round 11
// 220.147 us; speedup vs baseline: 1.0773x; 1.0654x over previous
//
#include <hip/hip_runtime.h>

typedef unsigned short u16;
typedef __attribute__((ext_vector_type(8))) _Float16 half8;
typedef __attribute__((ext_vector_type(2))) __fp16 fp16x2;
typedef __attribute__((ext_vector_type(4))) float f32x4;
typedef __attribute__((ext_vector_type(16))) float f32x16;

#define MFMAH(A,B,C) __builtin_amdgcn_mfma_f32_16x16x32_f16(A,B,C,0,0,0)
#define MFMA32(A,B,C) __builtin_amdgcn_mfma_f32_32x32x16_f16(A,B,C,0,0,0)
#define LOG2E 1.4426950408889634f
#define C1 0.18033688011112042f   // 0.125 * log2(e)

__device__ __forceinline__ u16 f2h(float f){
  _Float16 h = (_Float16)f; u16 r; __builtin_memcpy(&r,&h,2); return r;
}
__device__ __forceinline__ float h2f(u16 v){
  _Float16 h; __builtin_memcpy(&h,&v,2); return (float)h;
}
__device__ __forceinline__ unsigned int pack_h2(float a, float b){
  fp16x2 h = __builtin_amdgcn_cvt_pkrtz(a,b);
  unsigned int r; __builtin_memcpy(&r,&h,4); return r;
}

// async global->LDS, 16B per lane; LDS dest = wave-uniform base + lane*16.
__device__ __forceinline__ void async_ld16(const void* g, void* l) {
  __builtin_amdgcn_global_load_lds(
      (const __attribute__((address_space(1))) unsigned int*)g,
      (__attribute__((address_space(3))) unsigned int*)l, 16, 0, 0);
}

// Cast hs (4M el) + Wq,Wk,Wv,Wo (1M each) fp32->f16 into contiguous ws.
__global__ __launch_bounds__(256) void cast_all(const float* __restrict__ hs,
    const float* __restrict__ wq, const float* __restrict__ wk,
    const float* __restrict__ wv, const float* __restrict__ wo,
    u16* __restrict__ dst)
{
  unsigned int i = blockIdx.x*256 + threadIdx.x;     // chunk of 8 elements
  size_t el = (size_t)i * 8;
  const float* src; size_t off;
  if (el < 4194304) { src = hs; off = el; }
  else {
    unsigned int r = (unsigned int)((el - 4194304) >> 20);
    src = (r==0)?wq:(r==1)?wk:(r==2)?wv:wo;
    off = (el - 4194304) & 1048575;
  }
  float4 a = *reinterpret_cast<const float4*>(src+off);
  float4 b = *reinterpret_cast<const float4*>(src+off+4);
  uint4 o = {pack_h2(a.x,a.y), pack_h2(a.z,a.w), pack_h2(b.x,b.y), pack_h2(b.z,b.w)};
  *reinterpret_cast<uint4*>(dst + el) = o;
}

// Fused QKV GEMM, 128x128 tiles, 24x32=768 blocks (3/CU). W=[Wq;Wk;Wv].
// which = n0>>10: 0/1 -> q/k (SWAPPED operands, d-contiguous packed stores into
// [bh][s][d]); 2 -> v (normal order, s-contiguous packed stores into V^T [bh][d][s]).
__global__ __launch_bounds__(256) void gemm_qkv(const u16* __restrict__ A,
                                                const u16* __restrict__ W,
                                                const float* __restrict__ bqp,
                                                const float* __restrict__ bkp,
                                                const float* __restrict__ bvp,
                                                u16* __restrict__ qout,
                                                u16* __restrict__ kout,
                                                u16* __restrict__ vout,
                                                int M, int K)
{
  __shared__ __align__(16) u16 lds_a[128*32];
  __shared__ __align__(16) u16 lds_w[128*32];
  const int t = threadIdx.x;
  const int lane = t & 63, wave = t >> 6;
  const int wm = wave >> 1, wn = wave & 1;
  const int lr = lane & 15, quad = lane >> 4;
  const int n0 = blockIdx.x * 128, m0 = blockIdx.y * 128;
  const int wbase = t & 192;
  const int which = n0 >> 10;

  const f32x4 fzero = {0.f,0.f,0.f,0.f};
  f32x4 acc[4][4];
  #pragma unroll
  for (int i=0;i<4;++i)
    #pragma unroll
    for (int j=0;j<4;++j) acc[i][j] = fzero;

  if (which < 2) {                 // ---- q/k: swapped operands, D[n][m] ----
    for (int k0 = 0; k0 < K; k0 += 32) {
      __syncthreads();
      #pragma unroll
      for (int it=0; it<2; ++it) {
        int idx = it*256 + t;
        int row = idx >> 2, c8 = (idx & 3) * 8;
        int lbase = (it*256 + wbase) * 8;
        async_ld16(&A[(size_t)(m0+row)*K + k0 + c8], &lds_a[lbase]);
        async_ld16(&W[(size_t)(n0+row)*K + k0 + c8], &lds_w[lbase]);
      }
      __syncthreads();
      half8 af[4], bfr[4];
      #pragma unroll
      for (int mt=0; mt<4; ++mt)
        af[mt] = *reinterpret_cast<const half8*>(&lds_a[(wm*64 + mt*16 + lr)*32 + quad*8]);
      #pragma unroll
      for (int nt=0; nt<4; ++nt)
        bfr[nt] = *reinterpret_cast<const half8*>(&lds_w[(wn*64 + nt*16 + lr)*32 + quad*8]);
      #pragma unroll
      for (int mt=0; mt<4; ++mt)
        #pragma unroll
        for (int nt=0; nt<4; ++nt)
          acc[mt][nt] = MFMAH(bfr[nt], af[mt], acc[mt][nt]);
    }
    const float* bp = which ? bkp : bqp;
    u16* dst = which ? kout : qout;
    #pragma unroll
    for (int nt=0; nt<4; ++nt) {
      int nn = (n0 & 1023) + wn*64 + nt*16 + quad*4;   // 4 consecutive n on regs
      float4 bv = *reinterpret_cast<const float4*>(&bp[nn]);
      int hh = nn >> 6, d4 = nn & 63;
      #pragma unroll
      for (int mt=0; mt<4; ++mt) {
        int m = m0 + wm*64 + mt*16 + lr;
        int b = m >> 11, s = m & 2047;
        uint2 o = {pack_h2(acc[mt][nt][0]+bv.x, acc[mt][nt][1]+bv.y),
                   pack_h2(acc[mt][nt][2]+bv.z, acc[mt][nt][3]+bv.w)};
        *reinterpret_cast<uint2*>(&dst[((size_t)(b*16 + hh)*2048 + s)*64 + d4]) = o;
      }
    }
  } else {                         // ---- v: normal order, D[m][n] -> V^T ----
    for (int k0 = 0; k0 < K; k0 += 32) {
      __syncthreads();
      #pragma unroll
      for (int it=0; it<2; ++it) {
        int idx = it*256 + t;
        int row = idx >> 2, c8 = (idx & 3) * 8;
        int lbase = (it*256 + wbase) * 8;
        async_ld16(&A[(size_t)(m0+row)*K + k0 + c8], &lds_a[lbase]);
        async_ld16(&W[(size_t)(n0+row)*K + k0 + c8], &lds_w[lbase]);
      }
      __syncthreads();
      half8 af[4], bfr[4];
      #pragma unroll
      for (int mt=0; mt<4; ++mt)
        af[mt] = *reinterpret_cast<const half8*>(&lds_a[(wm*64 + mt*16 + lr)*32 + quad*8]);
      #pragma unroll
      for (int nt=0; nt<4; ++nt)
        bfr[nt] = *reinterpret_cast<const half8*>(&lds_w[(wn*64 + nt*16 + lr)*32 + quad*8]);
      #pragma unroll
      for (int mt=0; mt<4; ++mt)
        #pragma unroll
        for (int nt=0; nt<4; ++nt)
          acc[mt][nt] = MFMAH(af[mt], bfr[nt], acc[mt][nt]);
    }
    #pragma unroll
    for (int nt=0; nt<4; ++nt) {
      int nn = (n0 & 1023) + wn*64 + nt*16 + lr;
      float bv = bvp[nn];
      int hh = nn >> 6, d = nn & 63;
      #pragma unroll
      for (int mt=0; mt<4; ++mt) {
        int m = m0 + wm*64 + mt*16 + quad*4;
        int b = m >> 11, s = m & 2047;
        uint2 o = {pack_h2(acc[mt][nt][0]+bv, acc[mt][nt][1]+bv),
                   pack_h2(acc[mt][nt][2]+bv, acc[mt][nt][3]+bv)};
        *reinterpret_cast<uint2*>(&vout[((size_t)(b*16 + hh)*64 + d)*2048 + s]) = o;
      }
    }
  }
}

// Out-proj GEMM, SWAPPED operands: lane holds 4 consecutive n -> float4 stores.
__global__ __launch_bounds__(256) void gemm_o(const u16* __restrict__ A,
                                              const u16* __restrict__ W,
                                              const float* __restrict__ bias,
                                              float* __restrict__ O,
                                              int M, int N, int K)
{
  __shared__ __align__(16) u16 lds_a[128*32];
  __shared__ __align__(16) u16 lds_w[64*32];
  const int t = threadIdx.x;
  const int lane = t & 63, wm = t >> 6;      // wave owns 32 M-rows
  const int lr = lane & 15, quad = lane >> 4;
  const int n0 = blockIdx.x * 64, m0 = blockIdx.y * 128;
  const int wbase = t & 192;

  const f32x4 fzero = {0.f,0.f,0.f,0.f};
  f32x4 acc[2][4];
  #pragma unroll
  for (int i=0;i<2;++i)
    #pragma unroll
    for (int j=0;j<4;++j) acc[i][j] = fzero;

  for (int k0 = 0; k0 < K; k0 += 32) {
    __syncthreads();
    #pragma unroll
    for (int it=0; it<2; ++it) {
      int idx = it*256 + t;
      int row = idx >> 2, c8 = (idx & 3) * 8;
      int lbase = (it*256 + wbase) * 8;
      async_ld16(&A[(size_t)(m0+row)*K + k0 + c8], &lds_a[lbase]);
    }
    async_ld16(&W[(size_t)(n0 + (t>>2))*K + k0 + (t&3)*8], &lds_w[wbase*8]);
    __syncthreads();
    half8 af[2], bfr[4];
    #pragma unroll
    for (int mt=0; mt<2; ++mt)
      af[mt] = *reinterpret_cast<const half8*>(&lds_a[(wm*32 + mt*16 + lr)*32 + quad*8]);
    #pragma unroll
    for (int nt=0; nt<4; ++nt)
      bfr[nt] = *reinterpret_cast<const half8*>(&lds_w[(nt*16 + lr)*32 + quad*8]);
    #pragma unroll
    for (int mt=0; mt<2; ++mt)
      #pragma unroll
      for (int nt=0; nt<4; ++nt)
        acc[mt][nt] = MFMAH(bfr[nt], af[mt], acc[mt][nt]);   // D[n][m]
  }

  #pragma unroll
  for (int nt=0; nt<4; ++nt) {
    int nb = n0 + nt*16 + quad*4;
    float4 bv = *reinterpret_cast<const float4*>(&bias[nb]);
    #pragma unroll
    for (int mt=0; mt<2; ++mt) {
      int m = m0 + wm*32 + mt*16 + lr;
      float4 o = {acc[mt][nt][0]+bv.x, acc[mt][nt][1]+bv.y,
                  acc[mt][nt][2]+bv.z, acc[mt][nt][3]+bv.w};
      *reinterpret_cast<float4*>(&O[(size_t)m * N + nb]) = o;
    }
  }
}

// In-place RMSNorm (over 1024 pre-split channels) + RoPE on [B,H,S,D] f16.
__global__ __launch_bounds__(128) void rmsrope(u16* __restrict__ qb, u16* __restrict__ kb,
                                               const float* __restrict__ cosb,
                                               const float* __restrict__ sinb,
                                               const float* __restrict__ w)
{
  u16* buf = blockIdx.y ? kb : qb;
  const int bs = blockIdx.x;
  const int b = bs >> 11, s = bs & 2047;
  const int t = threadIdx.x;                 // 128
  const int h = t >> 3, d0 = (t & 7) * 4;
  size_t base = ((size_t)(b*16+h)*2048 + s)*64;

  uint2 u1 = *reinterpret_cast<const uint2*>(&buf[base + d0]);
  uint2 u2 = *reinterpret_cast<const uint2*>(&buf[base + d0 + 32]);
  u16 a1[4], a2[4];
  __builtin_memcpy(a1, &u1, 8); __builtin_memcpy(a2, &u2, 8);
  float x1[4], x2[4];
  float ss = 0.f;
  #pragma unroll
  for (int j=0;j<4;++j){
    x1[j] = h2f(a1[j]); x2[j] = h2f(a2[j]);
    ss += x1[j]*x1[j] + x2[j]*x2[j];
  }
  #pragma unroll
  for (int off=32; off>0; off>>=1) ss += __shfl_xor(ss, off, 64);
  __shared__ float red[2];
  if ((t & 63) == 0) red[t>>6] = ss;
  __syncthreads();
  float tot = red[0] + red[1];
  float r = rsqrtf(tot * (1.0f/1024.0f) + 1e-6f);

  float4 w1 = *reinterpret_cast<const float4*>(&w[h*64+d0]);
  float4 w2 = *reinterpret_cast<const float4*>(&w[h*64+d0+32]);
  float4 c1 = *reinterpret_cast<const float4*>(&cosb[s*64+d0]);
  float4 s1 = *reinterpret_cast<const float4*>(&sinb[s*64+d0]);
  float4 c2 = *reinterpret_cast<const float4*>(&cosb[s*64+d0+32]);
  float4 s2 = *reinterpret_cast<const float4*>(&sinb[s*64+d0+32]);
  float n1[4] = {x1[0]*r*w1.x, x1[1]*r*w1.y, x1[2]*r*w1.z, x1[3]*r*w1.w};
  float n2[4] = {x2[0]*r*w2.x, x2[1]*r*w2.y, x2[2]*r*w2.z, x2[3]*r*w2.w};
  float o1[4] = {n1[0]*c1.x - n2[0]*s1.x, n1[1]*c1.y - n2[1]*s1.y,
                 n1[2]*c1.z - n2[2]*s1.z, n1[3]*c1.w - n2[3]*s1.w};
  float o2[4] = {n2[0]*c2.x + n1[0]*s2.x, n2[1]*c2.y + n1[1]*s2.y,
                 n2[2]*c2.z + n1[2]*s2.z, n2[3]*c2.w + n1[3]*s2.w};
  uint2 v1 = {pack_h2(o1[0],o1[1]), pack_h2(o1[2],o1[3])};
  uint2 v2 = {pack_h2(o2[0],o2[1]), pack_h2(o2[2],o2[3])};
  *reinterpret_cast<uint2*>(&buf[base + d0])      = v1;
  *reinterpret_cast<uint2*>(&buf[base + d0 + 32]) = v2;
}

// Flash attention with 32x32x16 MFMA (2x FLOP per LDS byte vs 16x16x32).
// BLOCK_Q=128, 4 waves x 32 q. S^T = K.Q^T (A=K,B=Q); O^T = V^T.P^T with vbuf
// in bit-swapped virtual-key order: vpos = key with bits 2<->3 swapped, so the
// S^T C-layout regs (row=(r&3)+8*(r>>2)+4*half) feed PV B-frags with no shuffles.
// Double-buffered LDS with register prefetch; one barrier per tile.
__global__ __launch_bounds__(256) void attn(const u16* __restrict__ qh,
                                            const u16* __restrict__ kh,
                                            const u16* __restrict__ vt,
                                            u16* __restrict__ ao)
{
  __shared__ __align__(16) u16 kbuf[2][64*72];   // [key][d], pad 72
  __shared__ __align__(16) u16 vbuf[2][64*72];   // [d][virtual-k], pad 72
  const int t = threadIdx.x;
  const int lane = t & 63, w = t >> 6;           // 4 waves
  const int ql = lane & 31, hf = lane >> 5;
  const int qbase = blockIdx.x * 128;
  const int bh = blockIdx.y;
  const int b = bh >> 4, h = bh & 15;
  const size_t hb = (size_t)bh * 2048 * 64;
  const u16* qp = qh + hb;
  const u16* kp = kh + hb;
  const u16* vtp = vt + hb;

  const int q_abs = qbase + w*32 + ql;
  half8 qf[4];                                   // B-frags: Q[d=s*16+hf*8+j][q=ql]
  #pragma unroll
  for (int s=0;s<4;++s)
    qf[s] = *reinterpret_cast<const half8*>(&qp[(size_t)q_abs*64 + s*16 + hf*8]);

  // staging: thread owns chunk cc of rows row and row+32 (K and V^T)
  const int row = t >> 3;                        // 0..31
  const int cc = t & 7;
  const int base2 = 32*(cc>>2) + 16*((cc>>1)&1) + 4*(cc&1);  // keys base2+{0..3,8..11}
  const int kofs = row*72 + cc*8;
  const u16* kg = kp + (size_t)row*64 + cc*8;
  const u16* vg = vtp + (size_t)row*2048 + base2;

  const f32x16 fz16 = {0.f,0.f,0.f,0.f,0.f,0.f,0.f,0.f,0.f,0.f,0.f,0.f,0.f,0.f,0.f,0.f};
  f32x16 oacc[2];
  oacc[0] = fz16; oacc[1] = fz16;
  float lsum = 0.f;
  const int diag = (qbase + w*32) >> 6;          // the one mixed tile for this wave

  // stage tile 0 into buffer 0
  {
    uint4 k0v = *reinterpret_cast<const uint4*>(kg);
    uint4 k1v = *reinterpret_cast<const uint4*>(kg + 32*64);
    uint2 a0 = *reinterpret_cast<const uint2*>(vg);
    uint2 a1 = *reinterpret_cast<const uint2*>(vg + 8);
    uint2 b0 = *reinterpret_cast<const uint2*>(vg + (size_t)32*2048);
    uint2 b1 = *reinterpret_cast<const uint2*>(vg + (size_t)32*2048 + 8);
    *reinterpret_cast<uint4*>(&kbuf[0][kofs])        = k0v;
    *reinterpret_cast<uint4*>(&kbuf[0][kofs+32*72])  = k1v;
    uint4 v0 = {a0.x,a0.y,a1.x,a1.y};
    uint4 v1 = {b0.x,b0.y,b1.x,b1.y};
    *reinterpret_cast<uint4*>(&vbuf[0][kofs])        = v0;
    *reinterpret_cast<uint4*>(&vbuf[0][kofs+32*72])  = v1;
  }

  for (int kt=0; kt<32; ++kt) {
    // prefetch next tile into registers (overlaps compute)
    uint4 k0n, k1n; uint2 a0n, a1n, b0n, b1n;
    if (kt < 31) {
      const u16* kgn = kg + (size_t)(kt+1)*4096;
      const u16* vgn = vg + (kt+1)*64;
      k0n = *reinterpret_cast<const uint4*>(kgn);
      k1n = *reinterpret_cast<const uint4*>(kgn + 32*64);
      a0n = *reinterpret_cast<const uint2*>(vgn);
      a1n = *reinterpret_cast<const uint2*>(vgn + 8);
      b0n = *reinterpret_cast<const uint2*>(vgn + (size_t)32*2048);
      b1n = *reinterpret_cast<const uint2*>(vgn + (size_t)32*2048 + 8);
    }
    __syncthreads();
    const u16* kb = kbuf[kt & 1];
    const u16* vb = vbuf[kt & 1];

    // S^T = K.Q^T  (two 32-key halves), then exp -> packed PV B-frags
    unsigned int pk[4][4];
    #pragma unroll
    for (int kh2=0; kh2<2; ++kh2) {
      f32x16 z = fz16;
      #pragma unroll
      for (int s=0;s<4;++s) {
        half8 kf;
        __builtin_memcpy(&kf, &kb[(kh2*32+ql)*72 + s*16 + hf*8], 16);
        z = MFMA32(kf, qf[s], z);
      }
      float p[16];
      if (kt != diag) {
        float ml = (kt < diag) ? LOG2E : 0.0f;
        #pragma unroll
        for (int r=0;r<16;++r) {
          p[r] = __builtin_amdgcn_exp2f(__builtin_fmaf(z[r], C1, ml));
          lsum += p[r];
        }
      } else {
        #pragma unroll
        for (int r=0;r<16;++r) {
          int key = kt*64 + kh2*32 + (r&3) + 8*(r>>2) + 4*hf;
          float ml = (key <= q_abs) ? LOG2E : 0.0f;
          p[r] = __builtin_amdgcn_exp2f(__builtin_fmaf(z[r], C1, ml));
          lsum += p[r];
        }
      }
      #pragma unroll
      for (int t2=0;t2<2;++t2)
        #pragma unroll
        for (int jj=0;jj<4;++jj)
          pk[kh2*2+t2][jj] = pack_h2(p[t2*8+jj*2], p[t2*8+jj*2+1]);
    }

    // O^T += V^T . P^T  (vbuf rows in virtual-k order)
    #pragma unroll
    for (int st=0;st<4;++st) {
      uint4 pq = {pk[st][0], pk[st][1], pk[st][2], pk[st][3]};
      half8 pf; __builtin_memcpy(&pf, &pq, 16);
      #pragma unroll
      for (int dh=0; dh<2; ++dh) {
        half8 vf;
        __builtin_memcpy(&vf, &vb[(dh*32+ql)*72 + st*16 + hf*8], 16);
        oacc[dh] = MFMA32(vf, pf, oacc[dh]);
      }
    }

    // write prefetched tile into the other buffer (visible after next barrier)
    if (kt < 31) {
      u16* kwn = &kbuf[(kt+1)&1][kofs];
      u16* vwn = &vbuf[(kt+1)&1][kofs];
      *reinterpret_cast<uint4*>(kwn)         = k0n;
      *reinterpret_cast<uint4*>(kwn + 32*72) = k1n;
      uint4 v0 = {a0n.x,a0n.y,a1n.x,a1n.y};
      uint4 v1 = {b0n.x,b0n.y,b1n.x,b1n.y};
      *reinterpret_cast<uint4*>(vwn)         = v0;
      *reinterpret_cast<uint4*>(vwn + 32*72) = v1;
    }
  }

  lsum += __shfl_xor(lsum, 32, 64);              // other key-half, same q
  float inv = 1.0f / lsum;
  size_t rowbase = ((size_t)(b*2048 + q_abs))*1024 + h*64;
  #pragma unroll
  for (int dh=0; dh<2; ++dh)
    #pragma unroll
    for (int rq=0; rq<4; ++rq) {
      int dd = dh*32 + 8*rq + 4*hf;
      uint2 o = {pack_h2(oacc[dh][rq*4+0]*inv, oacc[dh][rq*4+1]*inv),
                 pack_h2(oacc[dh][rq*4+2]*inv, oacc[dh][rq*4+3]*inv)};
      *reinterpret_cast<uint2*>(&ao[rowbase + dd]) = o;
    }
}

extern "C" void kernel_launch(void* const* d_in, const int* in_sizes, int n_in,
                              void* d_out, int out_size, void* d_ws, size_t ws_size,
                              hipStream_t stream)
{
  const float* hs   = (const float*)d_in[0];
  const float* cosb = (const float*)d_in[1];
  const float* sinb = (const float*)d_in[2];
  const float* Wq   = (const float*)d_in[3];
  const float* bq   = (const float*)d_in[4];
  const float* Wk   = (const float*)d_in[5];
  const float* bk   = (const float*)d_in[6];
  const float* Wv   = (const float*)d_in[7];
  const float* bv   = (const float*)d_in[8];
  const float* Wo   = (const float*)d_in[9];
  const float* bo   = (const float*)d_in[10];
  const float* rw   = (const float*)d_in[11];

  const size_t NEL = (size_t)4096 * 1024;   // 4M
  const size_t WEL = (size_t)1024 * 1024;   // 1M
  u16* hsb = (u16*)d_ws;                    // f16 hs [4096,1024]
  u16* wqb = hsb + NEL;                     // Wq,Wk,Wv contiguous; then Wo
  u16* wob = wqb + 3*WEL;
  u16* qhb = wob + WEL;                     // q,k head layout; v -> V^T [bh][d][s]
  u16* khb = qhb + NEL;
  u16* vtb = khb + NEL;
  u16* aob = hsb;                           // reuse: hs consumed by QKV GEMM

  cast_all<<<4096, 256, 0, stream>>>(hs, Wq, Wk, Wv, Wo, hsb);
  gemm_qkv<<<dim3(24,32), 256, 0, stream>>>(hsb, wqb, bq, bk, bv, qhb, khb, vtb, 4096, 1024);
  rmsrope<<<dim3(4096,2), 128, 0, stream>>>(qhb, khb, cosb, sinb, rw);
  attn<<<dim3(16,32), 256, 0, stream>>>(qhb, khb, vtb, aob);
  gemm_o<<<dim3(16,32), 256, 0, stream>>>(aob, wob, bo, (float*)d_out, 4096, 1024, 1024);
}